// Round 6
// baseline (115.100 us; speedup 1.0000x reference)
//
#include <hip/hip_runtime.h>
#include <math.h>

#define L_LEN  262144          // L = 2^18 = 512*512
#define NST    64
#define TPB    256
#define TSTR   544             // padded row stride (float2) for transpose staging
#define PI2F   6.2831853071795864769f
#define PIF    3.1415926535897932385f
#define R2C    0.70710678118654752440f

__device__ inline float2 cmul(float2 a, float2 b) {
    return make_float2(a.x*b.x - a.y*b.y, a.x*b.y + a.y*b.x);
}
__device__ inline float frcp(float x) { return __builtin_amdgcn_rcpf(x); }
__device__ inline float2 cadd(float2 a, float2 b) { return make_float2(a.x+b.x, a.y+b.y); }
__device__ inline float2 csub(float2 a, float2 b) { return make_float2(a.x-b.x, a.y-b.y); }

// Twiddle table (sign-agnostic, 576 float2 = 4.6KB):
//  [0,64):   (cos,sin) of 2*pi*r*q/64  , r=i>>3, q=i&7   (stage Ns=8)
//  [64,576): (cos,sin) of 2*pi*r*q/512 , r=ii>>3, q=ii&7 (stage Ns=64)
__device__ inline void twt_init(float2* twt) {
    for (int i = threadIdx.x; i < 576; i += TPB) {
        float ang;
        if (i < 64) ang = PI2F * (float)((i >> 3) * (i & 7)) * (1.0f / 64.0f);
        else { int ii = i - 64;
               ang = PI2F * (float)((ii >> 3) * (ii & 7)) * (1.0f / 512.0f); }
        float sn, cs; __sincosf(ang, &sn, &cs);
        twt[i] = make_float2(cs, sn);
    }
}

// NF independent length-512 FFTs in LDS, radix-8 Stockham (3 stages).
// Layout buf[f*512+i]; natural in/out; sgn=-1 fwd, +1 inv (unscaled).
// Twiddles: table lookup, w = (c, sgn*s). Starts/ends with __syncthreads().
template<int M, int NF>
__device__ float2* lds_fft_r8(float2* b0, float2* b1, float sgn, const float2* twt) {
    float2* src = b0; float2* dst = b1;
    for (int Ns = 1; Ns * 8 <= M; Ns <<= 3) {
        __syncthreads();
        const int NB = NF * (M / 8);
        for (int bi = threadIdx.x; bi < NB; bi += TPB) {
            int f = bi / (M / 8);
            int j = bi & (M / 8 - 1);
            int r = j & (Ns - 1);
            const float2* s = src + f * M;
            float2 x[8];
            #pragma unroll
            for (int q = 0; q < 8; ++q) x[q] = s[j + q * (M / 8)];
            if (Ns > 1) {
                const float2* tw = twt + ((Ns == 8) ? 0 : 64) + (r << 3);
                #pragma unroll
                for (int q = 1; q < 8; ++q) {
                    float2 w = tw[q];
                    float wc = w.x, ws = sgn * w.y;
                    x[q] = make_float2(x[q].x*wc - x[q].y*ws,
                                       x[q].x*ws + x[q].y*wc);
                }
            }
            // 8-pt DFT, kernel e^{sgn*2pi*i*pq/8}
            float2 E[4], O[4];
            {   // even inputs x0,x2,x4,x6
                float2 t0 = cadd(x[0], x[4]), t1 = csub(x[0], x[4]);
                float2 t2 = cadd(x[2], x[6]), t3 = csub(x[2], x[6]);
                E[0] = cadd(t0, t2); E[2] = csub(t0, t2);
                float2 it3 = make_float2(-sgn * t3.y, sgn * t3.x);
                E[1] = cadd(t1, it3); E[3] = csub(t1, it3);
            }
            {   // odd inputs x1,x3,x5,x7
                float2 t0 = cadd(x[1], x[5]), t1 = csub(x[1], x[5]);
                float2 t2 = cadd(x[3], x[7]), t3 = csub(x[3], x[7]);
                O[0] = cadd(t0, t2); O[2] = csub(t0, t2);
                float2 it3 = make_float2(-sgn * t3.y, sgn * t3.x);
                O[1] = cadd(t1, it3); O[3] = csub(t1, it3);
            }
            // combine: y_p = E_p + w8^p O_p ; y_{p+4} = E_p - w8^p O_p
            float2 w1o = make_float2(R2C * (O[1].x - sgn * O[1].y),
                                     R2C * (sgn * O[1].x + O[1].y));
            float2 w2o = make_float2(-sgn * O[2].y, sgn * O[2].x);
            float2 w3o = make_float2(R2C * (-O[3].x - sgn * O[3].y),
                                     R2C * (sgn * O[3].x - O[3].y));
            float2* d = dst + f * M + ((j - r) << 3) + r;
            d[0]      = cadd(E[0], O[0]);
            d[Ns]     = cadd(E[1], w1o);
            d[2 * Ns] = cadd(E[2], w2o);
            d[3 * Ns] = cadd(E[3], w3o);
            d[4 * Ns] = csub(E[0], O[0]);
            d[5 * Ns] = csub(E[1], w1o);
            d[6 * Ns] = csub(E[2], w2o);
            d[7 * Ns] = csub(E[3], w3o);
        }
        float2* tswp = src; src = dst; dst = tswp;
    }
    __syncthreads();
    return src;
}

// ---- kI: 1024 blocks.
//  b in [0,512): column c=b: pole/atroots (512 pts, 2/thread) + Acm store
//                + A ifft pass1 (NF=1) -> T_K scatter.
//  b in [512,1024): column c=b-512: u & u*tw fwd pass1 (NF=2) -> T_U, T_Uo.
__global__ __launch_bounds__(TPB, 4) void kI(
    const float* __restrict__ u,
    const float* __restrict__ Lre, const float* __restrict__ Lim,
    const float* __restrict__ Pre, const float* __restrict__ Pim,
    const float* __restrict__ Bre, const float* __restrict__ Bim,
    const float* __restrict__ Cri, const float* __restrict__ lstp,
    float2* __restrict__ Acm, float2* __restrict__ T_K,
    float2* __restrict__ T_U, float2* __restrict__ T_Uo)
{
    __shared__ float2 b0[1024], b1[1024];
    __shared__ float2 twt[576];
    __shared__ float4 cA[NST], cB[NST], cC[NST], cD[NST];
    const int t = threadIdx.x, bx = blockIdx.x;
    const float invL = 1.0f / (float)L_LEN;
    twt_init(twt);
    if (bx < 512) {
        const int c = bx;
        if (t < NST) {
            float lr = Lre[t], li = Lim[t];
            float pr = Pre[t], pi = Pim[t];
            float br = Bre[t], bi = Bim[t];
            float cr = Cri[2*t], ci = Cri[2*t+1];
            float dx = -lr;
            float v00x = cr*br + ci*bi, v00y = cr*bi - ci*br;   // conj(C)*B
            float v01x = cr*pr + ci*pi, v01y = cr*pi - ci*pr;   // conj(C)*P
            float v10x = pr*br + pi*bi, v10y = pr*bi - pi*br;   // conj(P)*B
            float v11x = pr*pr + pi*pi;                         // conj(P)*P
            cA[t] = make_float4(li, dx*dx, dx*v11x, -v11x);
            cB[t] = make_float4(dx*v00x, v00y, dx*v00y, -v00x);
            cC[t] = make_float4(dx*v01x, v01y, dx*v01y, -v01x);
            cD[t] = make_float4(dx*v10x, v10y, dx*v10y, -v10x);
        }
        __syncthreads();
        float G2 = 2.0f / expf(lstp[0]);
        float tn[2], gi[2], acc[2][8];
        #pragma unroll
        for (int p = 0; p < 2; ++p) {
            int e = t + (p << 8);
            int m = c + (e << 9);
            float h = PIF * ((float)m * invL);
            float sn, cs; __sincosf(h, &sn, &cs);
            float tv = sn * frcp(cs);
            tv = fminf(fmaxf(tv, -1e7f), 1e7f);  // pole guard (m=L/2: cos==0)
            tn[p] = tv; gi[p] = G2 * tv;
            #pragma unroll
            for (int q = 0; q < 8; ++q) acc[p][q] = 0.f;
        }
        #pragma unroll 2
        for (int n = 0; n < NST; ++n) {
            float4 a = cA[n], b = cB[n], cc = cC[n], d = cD[n];
            #pragma unroll
            for (int p = 0; p < 2; ++p) {
                float dy   = gi[p] - a.x;
                float iv   = frcp(fmaf(dy, dy, a.y));
                float ivdy = iv * dy;
                acc[p][6] = fmaf(iv, a.z, acc[p][6]);
                acc[p][7] = fmaf(ivdy, a.w, acc[p][7]);
                acc[p][0] = fmaf(iv, b.x,  fmaf(ivdy, b.y,  acc[p][0]));
                acc[p][1] = fmaf(iv, b.z,  fmaf(ivdy, b.w,  acc[p][1]));
                acc[p][2] = fmaf(iv, cc.x, fmaf(ivdy, cc.y, acc[p][2]));
                acc[p][3] = fmaf(iv, cc.z, fmaf(ivdy, cc.w, acc[p][3]));
                acc[p][4] = fmaf(iv, d.x,  fmaf(ivdy, d.y,  acc[p][4]));
                acc[p][5] = fmaf(iv, d.z,  fmaf(ivdy, d.w,  acc[p][5]));
            }
        }
        #pragma unroll
        for (int p = 0; p < 2; ++p) {
            int e = t + (p << 8);
            float ax = 1.f + acc[p][6], ay = acc[p][7];
            float im = frcp(ax*ax + ay*ay);
            float tx = acc[p][2]*acc[p][4] - acc[p][3]*acc[p][5];
            float ty = acc[p][2]*acc[p][5] + acc[p][3]*acc[p][4];
            float wx = acc[p][0] - (tx*ax + ty*ay) * im;
            float wy = acc[p][1] - (ty*ax - tx*ay) * im;
            float2 A = make_float2(wx - tn[p]*wy, wy + tn[p]*wx); // (1+i*tan)*w
            Acm[(c << 9) + e] = A;                 // contiguous store
            b0[e] = A;
        }
        float2* rA = lds_fft_r8<512, 1>(b0, b1, +1.f, twt);
        for (int k = t; k < 512; k += TPB) {
            float ang = PI2F * ((float)(c * k) * invL);
            float sn, cs; __sincosf(ang, &sn, &cs);
            T_K[k * TSTR + c] = cmul(make_float2(cs, sn), rA[k]);
        }
    } else {
        const int c = bx - 512;
        float uv0 = u[c + (t << 9)];
        float uv1 = u[c + ((t + 256) << 9)];
        {
            int n0 = c + (t << 9), n1 = c + ((t + 256) << 9);
            float sn, cs;
            __sincosf(PIF * ((float)n0 * invL), &sn, &cs);
            b0[t]        = make_float2(uv0, 0.f);
            b0[512 + t]  = make_float2(uv0 * cs, -uv0 * sn);
            __sincosf(PIF * ((float)n1 * invL), &sn, &cs);
            b0[t + 256]       = make_float2(uv1, 0.f);
            b0[512 + t + 256] = make_float2(uv1 * cs, -uv1 * sn);
        }
        float2* rU = lds_fft_r8<512, 2>(b0, b1, -1.f, twt);
        for (int i = t; i < 1024; i += TPB) {
            int v = i >> 9, k = i & 511;
            float ang = -PI2F * ((float)(c * k) * invL);
            float sn, cs; __sincosf(ang, &sn, &cs);
            float2 val = cmul(make_float2(cs, sn), rU[(v << 9) + k]);
            if (v == 0) T_U [k * TSTR + c] = val;
            else        T_Uo[k * TSTR + c] = val;
        }
    }
}

// ---- kII: 256 blocks, K-chain only, 2 columns per block (coalesced scatter):
//   rows c0=2b, c0+1: T_K p2 (ifft, NF=2) -> K -> K*tw -> fwd p1 (NF=2)
//   -> T_Ko scatter in 16B runs.
__global__ __launch_bounds__(TPB, 4) void kII(
    const float2* __restrict__ T_K, float2* __restrict__ T_Ko)
{
    __shared__ float2 b0[1024], b1[1024];
    __shared__ float2 twt[576];
    const int t = threadIdx.x, bx = blockIdx.x;
    const int c0 = bx << 1;
    const float invL = 1.0f / (float)L_LEN;
    twt_init(twt);
    for (int i = t; i < 1024; i += TPB)
        b0[i] = T_K[(c0 + (i >> 9)) * TSTR + (i & 511)];   // contiguous rows
    float2* rK = lds_fft_r8<512, 2>(b0, b1, +1.f, twt);
    float2* o = (rK == b0) ? b1 : b0;
    for (int i = t; i < 1024; i += TPB) {
        int f = i >> 9, e = i & 511;
        int n = (c0 + f) + (e << 9);
        float K = rK[i].x * invL;                 // Re(ifft)/L
        float sn, cs; __sincosf(PIF * ((float)n * invL), &sn, &cs);
        o[i] = make_float2(K * cs, -K * sn);      // K * e^{-i pi n/L}
    }
    float2* r2 = lds_fft_r8<512, 2>(o, rK, -1.f, twt);
    for (int i = t; i < 1024; i += TPB) {
        int f = i & 1, k = i >> 1;                // consecutive threads: c pairs
        int c = c0 + f;
        float ang = -PI2F * ((float)(c * k) * invL);
        float sn, cs; __sincosf(ang, &sn, &cs);
        T_Ko[k * TSTR + c] = cmul(make_float2(cs, sn), r2[(f << 9) + k]);
    }
}

// ---- kIII: 1024 blocks. U pass2 fused in (Ue/Uo arrays eliminated).
//  b in [0,512): row kc=b: {T_Ko,T_Uo} rows p2 (NF=2, fwd) -> Ko,Uo_row ;
//                Vo = Uo_row*Ko ; inv p1 -> T_Vo scatter.
//  b in [512,1024): row kc=b-512: T_U row p2 (fwd) -> Ue_row ;
//                Ve = Ue_row*Acm ; inv p1 -> T_Ve scatter.
__global__ __launch_bounds__(TPB, 4) void kIII(
    const float2* __restrict__ T_Ko, const float2* __restrict__ T_U,
    const float2* __restrict__ T_Uo, const float2* __restrict__ Acm,
    float2* __restrict__ T_Ve, float2* __restrict__ T_Vo)
{
    __shared__ float2 b0[1024], b1[1024];
    __shared__ float2 twt[576];
    const int t = threadIdx.x, bx = blockIdx.x;
    const float invL = 1.0f / (float)L_LEN;
    twt_init(twt);
    if (bx < 512) {
        const int kc = bx;
        for (int i = t; i < 1024; i += TPB) {
            int f = i >> 9, e = i & 511;
            b0[i] = f ? T_Uo[kc * TSTR + e] : T_Ko[kc * TSTR + e];
        }
        float2* r = lds_fft_r8<512, 2>(b0, b1, -1.f, twt);  // [0,512)=Ko, rest=Uo
        float2* o3 = (r == b0) ? b1 : b0;
        for (int i = t; i < 512; i += TPB)
            o3[i] = cmul(r[512 + i], r[i]);                 // Vo = Uo_row * Ko
        float2* rV = lds_fft_r8<512, 1>(o3, r, +1.f, twt);
        for (int k = t; k < 512; k += TPB) {
            float ang = PI2F * ((float)(kc * k) * invL);
            float sn, cs; __sincosf(ang, &sn, &cs);
            T_Vo[k * TSTR + kc] = cmul(make_float2(cs, sn), rV[k]);
        }
    } else {
        const int kc = bx - 512;
        for (int i = t; i < 512; i += TPB)
            b0[i] = T_U[kc * TSTR + i];
        float2* r = lds_fft_r8<512, 1>(b0, b1, -1.f, twt);  // Ue_row
        float2* o3 = (r == b0) ? b1 : b0;
        for (int i = t; i < 512; i += TPB)
            o3[i] = cmul(r[i], Acm[(kc << 9) + i]);         // Ve = Ue_row * A
        float2* rV = lds_fft_r8<512, 1>(o3, r, +1.f, twt);
        for (int k = t; k < 512; k += TPB) {
            float ang = PI2F * ((float)(kc * k) * invL);
            float sn, cs; __sincosf(ang, &sn, &cs);
            T_Ve[k * TSTR + kc] = cmul(make_float2(cs, sn), rV[k]);
        }
    }
}

// ---- kIV: 512 blocks, one row k/block: inv pass2 (NF=2) + combine + D*u -> out
__global__ __launch_bounds__(TPB, 4) void kIV(
    const float2* __restrict__ T_Ve, const float2* __restrict__ T_Vo,
    const float* __restrict__ u, const float* __restrict__ Dp,
    float* __restrict__ out)
{
    __shared__ float2 b0[1024], b1[1024];
    __shared__ float2 twt[576];
    const int t = threadIdx.x, k = blockIdx.x;
    const float invL = 1.0f / (float)L_LEN;
    twt_init(twt);
    for (int i = t; i < 512; i += TPB) {
        b0[i]       = T_Ve[k * TSTR + i];                   // contiguous
        b0[i + 512] = T_Vo[k * TSTR + i];
    }
    float2* r = lds_fft_r8<512, 2>(b0, b1, +1.f, twt);      // [0,512)=yE, rest yO
    const float sc = 0.5f * invL;                           // 1/(2L)
    const float D = Dp[0];
    for (int o1 = t; o1 < 512; o1 += TPB) {
        int n = k + (o1 << 9);
        float sn, cs; __sincosf(PIF * ((float)n * invL), &sn, &cs);
        float2 yE = r[o1];
        float2 yO = r[o1 + 512];
        // y = (yE.re + Re(e^{+i pi n/L} * yO)) / (2L) + D*u
        out[n] = fmaf(D, u[n], (yE.x + cs * yO.x - sn * yO.y) * sc);
    }
}

extern "C" void kernel_launch(void* const* d_in, const int* in_sizes, int n_in,
                              void* d_out, int out_size, void* d_ws, size_t ws_size,
                              hipStream_t stream) {
    const float* u    = (const float*)d_in[0];
    const float* Lre  = (const float*)d_in[1];
    const float* Lim  = (const float*)d_in[2];
    const float* Pre  = (const float*)d_in[3];
    const float* Pim  = (const float*)d_in[4];
    const float* Bre  = (const float*)d_in[5];
    const float* Bim  = (const float*)d_in[6];
    const float* Cri  = (const float*)d_in[7];
    const float* Dp   = (const float*)d_in[8];
    const float* lstp = (const float*)d_in[9];
    float* out = (float*)d_out;

    // Workspace (~15.5 MB): Acm 512-stride (2MB); TSTR arrays 0x220000 each.
    // Ue/Uo eliminated (U pass2 fused into kIII).
    char* ws = (char*)d_ws;
    float2* Acm  = (float2*)(ws);                    // 512-stride
    float2* T_K  = (float2*)(ws + 0x200000);         // TSTR-stride
    float2* T_U  = (float2*)(ws + 0x420000);         // TSTR-stride
    float2* T_Uo = (float2*)(ws + 0x640000);         // TSTR-stride
    float2* T_Ko = (float2*)(ws + 0x860000);         // TSTR-stride
    float2* T_Ve = (float2*)(ws + 0xA80000);         // TSTR-stride
    float2* T_Vo = (float2*)(ws + 0xCA0000);         // TSTR-stride

    kI  <<<1024, TPB, 0, stream>>>(u, Lre,Lim,Pre,Pim,Bre,Bim,Cri,lstp,
                                   Acm, T_K, T_U, T_Uo);
    kII <<< 256, TPB, 0, stream>>>(T_K, T_Ko);
    kIII<<<1024, TPB, 0, stream>>>(T_Ko, T_U, T_Uo, Acm, T_Ve, T_Vo);
    kIV <<< 512, TPB, 0, stream>>>(T_Ve, T_Vo, u, Dp, out);
}